// Round 3
// baseline (316.772 us; speedup 1.0000x reference)
//
#include <hip/hip_runtime.h>
#include <hip/hip_bf16.h>
#include <math.h>

#define B_ 8
#define S_ 4096
#define H_ 1024
#define M_ 256
#define R_ (B_*M_)   // 2048 rows of the cell matrix

typedef __attribute__((ext_vector_type(8))) short short8;
typedef __attribute__((ext_vector_type(4))) float f32x4;

__device__ __forceinline__ unsigned short f2bf(float x) {
  union { float f; unsigned int u; } v; v.f = x;
  unsigned int r = v.u + 0x7FFF + ((v.u >> 16) & 1);   // RNE
  return (unsigned short)(r >> 16);
}
__device__ __forceinline__ float bf2f(unsigned short h) {
  union { unsigned int u; float f; } v; v.u = ((unsigned int)h) << 16;
  return v.f;
}
__device__ __forceinline__ int get_id(const void* tt, int is64, int idx) {
  return is64 ? (int)((const long long*)tt)[idx] : ((const int*)tt)[idx];
}

// ---------------- Kernel 0: detect whether token ids are int64 or int32 ------
// ids are in [0,256). If buffer is int64 (LE), every odd 32-bit word is 0.
// If int32, 128 consecutive odd words all being real ids AND all zero has
// probability 256^-128 ~ 0. Write flag: 1 = int64, 0 = int32.
__global__ __launch_bounds__(128) void detect64(const unsigned int* __restrict__ tt32,
                                                int* __restrict__ flag) {
  __shared__ int any;
  if (threadIdx.x == 0) any = 0;
  __syncthreads();
  if (tt32[threadIdx.x * 2 + 1] != 0u) atomicOr(&any, 1);
  __syncthreads();
  if (threadIdx.x == 0) *flag = any ? 0 : 1;
}

// ---------------- Kernel 1: segment sum per (b,m) -> split bf16 cell ---------
__global__ __launch_bounds__(256) void seg_sum(const float* __restrict__ hidden,
                                               const void* __restrict__ tt,
                                               const int* __restrict__ flag,
                                               unsigned short* __restrict__ chi,
                                               unsigned short* __restrict__ clo) {
  const int bm = blockIdx.x;        // 0..2047
  const int b  = bm >> 8;
  const int m  = bm & (M_ - 1);
  __shared__ int list[S_];
  __shared__ int cnt;
  const int t = threadIdx.x;
  if (t == 0) cnt = 0;
  __syncthreads();
  const int is64 = *flag;           // uniform
  const int base = b * S_;
  #pragma unroll
  for (int c = 0; c < S_ / 256; ++c) {
    int s = c * 256 + t;
    if (get_id(tt, is64, base + s) == m) { int p = atomicAdd(&cnt, 1); list[p] = s; }
  }
  __syncthreads();
  const int n = cnt;
  float ax = 0.f, ay = 0.f, az = 0.f, aw = 0.f;
  const float4* hb = reinterpret_cast<const float4*>(hidden + (size_t)b * S_ * H_);
  for (int i = 0; i < n; ++i) {
    const int s = list[i];
    float4 v = hb[(size_t)s * (H_ / 4) + t];
    ax += v.x; ay += v.y; az += v.z; aw += v.w;
  }
  ushort4 hi, lo;
  hi.x = f2bf(ax); lo.x = f2bf(ax - bf2f(hi.x));
  hi.y = f2bf(ay); lo.y = f2bf(ay - bf2f(hi.y));
  hi.z = f2bf(az); lo.z = f2bf(az - bf2f(hi.z));
  hi.w = f2bf(aw); lo.w = f2bf(aw - bf2f(hi.w));
  *reinterpret_cast<ushort4*>(chi + (size_t)bm * H_ + t * 4) = hi;
  *reinterpret_cast<ushort4*>(clo + (size_t)bm * H_ + t * 4) = lo;
}

// ---------------- Kernel 2: W (f32) -> split bf16 ----------------
__global__ __launch_bounds__(256) void wconv(const float* __restrict__ W,
                                             unsigned short* __restrict__ whi,
                                             unsigned short* __restrict__ wlo) {
  int i = blockIdx.x * 256 + threadIdx.x;  // over H*H/4
  float4 v = reinterpret_cast<const float4*>(W)[i];
  ushort4 hi, lo;
  hi.x = f2bf(v.x); lo.x = f2bf(v.x - bf2f(hi.x));
  hi.y = f2bf(v.y); lo.y = f2bf(v.y - bf2f(hi.y));
  hi.z = f2bf(v.z); lo.z = f2bf(v.z - bf2f(hi.z));
  hi.w = f2bf(v.w); lo.w = f2bf(v.w - bf2f(hi.w));
  reinterpret_cast<ushort4*>(whi)[i] = hi;
  reinterpret_cast<ushort4*>(wlo)[i] = lo;
}

// ------- Kernel 3: cell2 = gelu(cell @ W^T + b), split-bf16 MFMA (3 products)
// A = cell [R_][H_] (K contiguous), B = W [out][K] (K contiguous) -> NT GEMM.
// Wave tile 32x64 (2x4 frags of 16x16), 4 waves 2x2 -> block 64x128; grid 32x8.
__global__ __launch_bounds__(256) void gemm_gelu(const unsigned short* __restrict__ Ahi,
                                                 const unsigned short* __restrict__ Alo,
                                                 const unsigned short* __restrict__ Bhi,
                                                 const unsigned short* __restrict__ Blo,
                                                 const float* __restrict__ bias,
                                                 float* __restrict__ C) {
  const int lane = threadIdx.x & 63;
  const int wid  = threadIdx.x >> 6;
  const int wm = wid >> 1, wn = wid & 1;
  const int rowBase = blockIdx.x * 64 + wm * 32;
  const int colBase = blockIdx.y * 128 + wn * 64;
  const int lr = lane & 15;   // row (A) / col (B) within fragment
  const int kg = lane >> 4;   // k-group (8 bf16 each)

  f32x4 acc[2][4];
  #pragma unroll
  for (int mi = 0; mi < 2; ++mi)
    #pragma unroll
    for (int ni = 0; ni < 4; ++ni)
      acc[mi][ni] = (f32x4){0.f, 0.f, 0.f, 0.f};

  for (int k0 = 0; k0 < H_; k0 += 32) {
    short8 ah[2], al[2], bh[4], bl[4];
    #pragma unroll
    for (int mi = 0; mi < 2; ++mi) {
      const size_t off = (size_t)(rowBase + mi * 16 + lr) * H_ + k0 + kg * 8;
      ah[mi] = *reinterpret_cast<const short8*>(Ahi + off);
      al[mi] = *reinterpret_cast<const short8*>(Alo + off);
    }
    #pragma unroll
    for (int ni = 0; ni < 4; ++ni) {
      const size_t off = (size_t)(colBase + ni * 16 + lr) * H_ + k0 + kg * 8;
      bh[ni] = *reinterpret_cast<const short8*>(Bhi + off);
      bl[ni] = *reinterpret_cast<const short8*>(Blo + off);
    }
    #pragma unroll
    for (int mi = 0; mi < 2; ++mi)
      #pragma unroll
      for (int ni = 0; ni < 4; ++ni) {
        acc[mi][ni] = __builtin_amdgcn_mfma_f32_16x16x32_bf16(ah[mi], bh[ni], acc[mi][ni], 0, 0, 0);
        acc[mi][ni] = __builtin_amdgcn_mfma_f32_16x16x32_bf16(ah[mi], bl[ni], acc[mi][ni], 0, 0, 0);
        acc[mi][ni] = __builtin_amdgcn_mfma_f32_16x16x32_bf16(al[mi], bh[ni], acc[mi][ni], 0, 0, 0);
      }
  }

  const float cg = 0.7978845608028654f;  // sqrt(2/pi)
  #pragma unroll
  for (int mi = 0; mi < 2; ++mi) {
    #pragma unroll
    for (int ni = 0; ni < 4; ++ni) {
      const int col = colBase + ni * 16 + lr;
      const float bv = bias[col];
      #pragma unroll
      for (int j = 0; j < 4; ++j) {
        const int row = rowBase + mi * 16 + kg * 4 + j;   // C/D: col=lane&15, row=(lane>>4)*4+j
        float x = acc[mi][ni][j] + bv;
        float g = 0.5f * x * (1.0f + tanhf(cg * (x + 0.044715f * x * x * x)));
        C[(size_t)row * H_ + col] = g;
      }
    }
  }
}

// ---------------- Kernel 4: gather rows back to sequence ----------------
__global__ __launch_bounds__(256) void gather_rows(const float* __restrict__ cell2,
                                                   const void* __restrict__ tt,
                                                   const int* __restrict__ flag,
                                                   float* __restrict__ out) {
  const int row = blockIdx.x;          // b*S + s
  const int b   = row >> 12;           // / 4096
  const int m   = get_id(tt, *flag, row);
  const float4* src = reinterpret_cast<const float4*>(cell2 + (size_t)(b * M_ + m) * H_);
  float4* dst = reinterpret_cast<float4*>(out + (size_t)row * H_);
  dst[threadIdx.x] = src[threadIdx.x];
}

extern "C" void kernel_launch(void* const* d_in, const int* in_sizes, int n_in,
                              void* d_out, int out_size, void* d_ws, size_t ws_size,
                              hipStream_t stream) {
  const float* hidden = (const float*)d_in[0];
  const void*  tt     = d_in[1];
  const float* W      = (const float*)d_in[2];
  const float* bias   = (const float*)d_in[3];
  float* out = (float*)d_out;

  char* ws = (char*)d_ws;
  int* flag = (int*)ws;
  unsigned short* chi = (unsigned short*)(ws + 256);
  unsigned short* clo = chi + (size_t)R_ * H_;
  unsigned short* whi = clo + (size_t)R_ * H_;
  unsigned short* wlo = whi + (size_t)H_ * H_;
  float*          cell2 = (float*)(wlo + (size_t)H_ * H_);

  detect64<<<dim3(1), dim3(128), 0, stream>>>((const unsigned int*)tt, flag);
  seg_sum<<<dim3(R_), dim3(256), 0, stream>>>(hidden, tt, flag, chi, clo);
  wconv<<<dim3(H_ * H_ / 1024), dim3(256), 0, stream>>>(W, whi, wlo);
  gemm_gelu<<<dim3(R_ / 64, H_ / 128), dim3(256), 0, stream>>>(chi, clo, whi, wlo, bias, cell2);
  gather_rows<<<dim3(B_ * S_), dim3(256), 0, stream>>>(cell2, tt, flag, out);
}

// Round 4
// 313.301 us; speedup vs baseline: 1.0111x; 1.0111x over previous
//
#include <hip/hip_runtime.h>
#include <hip/hip_bf16.h>
#include <math.h>

#define B_ 8
#define S_ 4096
#define H_ 1024
#define M_ 256
#define R_ (B_*M_)   // 2048 rows of the cell matrix

typedef __attribute__((ext_vector_type(8))) short short8;
typedef __attribute__((ext_vector_type(4))) float f32x4;

__device__ __forceinline__ unsigned short f2bf(float x) {
  union { float f; unsigned int u; } v; v.f = x;
  unsigned int r = v.u + 0x7FFF + ((v.u >> 16) & 1);   // RNE
  return (unsigned short)(r >> 16);
}
__device__ __forceinline__ float bf2f(unsigned short h) {
  union { unsigned int u; float f; } v; v.u = ((unsigned int)h) << 16;
  return v.f;
}
__device__ __forceinline__ int get_id(const void* tt, int is64, int idx) {
  return is64 ? (int)((const long long*)tt)[idx] : ((const int*)tt)[idx];
}

// ------- Kernel 1: W (f32) -> split bf16; block 0 also detects id width ------
// ids are in [0,256). If the id buffer is int64 (LE), all odd 32-bit words are
// 0; if int32, 64 consecutive odd words all zero has prob 256^-64 ~ 0.
// flag: 1 = int64, 0 = int32. Launched first; stream order makes the flag
// visible to seg_sum / gather_rows.
__global__ __launch_bounds__(256) void wconv_detect(const float* __restrict__ W,
                                                    const unsigned int* __restrict__ tt32,
                                                    unsigned short* __restrict__ whi,
                                                    unsigned short* __restrict__ wlo,
                                                    int* __restrict__ flag) {
  if (blockIdx.x == 0 && threadIdx.x < 64) {
    unsigned long long any = __ballot(tt32[threadIdx.x * 2 + 1] != 0u);
    if (threadIdx.x == 0) *flag = (any == 0ull) ? 1 : 0;
  }
  int i = blockIdx.x * 256 + threadIdx.x;  // over H*H/4
  float4 v = reinterpret_cast<const float4*>(W)[i];
  ushort4 hi, lo;
  hi.x = f2bf(v.x); lo.x = f2bf(v.x - bf2f(hi.x));
  hi.y = f2bf(v.y); lo.y = f2bf(v.y - bf2f(hi.y));
  hi.z = f2bf(v.z); lo.z = f2bf(v.z - bf2f(hi.z));
  hi.w = f2bf(v.w); lo.w = f2bf(v.w - bf2f(hi.w));
  reinterpret_cast<ushort4*>(whi)[i] = hi;
  reinterpret_cast<ushort4*>(wlo)[i] = lo;
}

// ---------------- Kernel 2: segment sum per (b,m) -> split bf16 cell ---------
// One block per (b,m). Threads scan the row's token ids into an LDS match
// list, then cooperatively sum matching hidden rows (float4/thread = 4KB row).
__global__ __launch_bounds__(256) void seg_sum(const float* __restrict__ hidden,
                                               const void* __restrict__ tt,
                                               const int* __restrict__ flag,
                                               unsigned short* __restrict__ chi,
                                               unsigned short* __restrict__ clo) {
  const int bm = blockIdx.x;        // 0..2047
  const int b  = bm >> 8;
  const int m  = bm & (M_ - 1);
  __shared__ int list[S_];
  __shared__ int cnt;
  const int t = threadIdx.x;
  if (t == 0) cnt = 0;
  __syncthreads();
  const int is64 = *flag;           // uniform
  const int base = b * S_;
  #pragma unroll
  for (int c = 0; c < S_ / 256; ++c) {
    int s = c * 256 + t;
    if (get_id(tt, is64, base + s) == m) { int p = atomicAdd(&cnt, 1); list[p] = s; }
  }
  __syncthreads();
  const int n = cnt;
  float ax = 0.f, ay = 0.f, az = 0.f, aw = 0.f;
  const float4* hb = reinterpret_cast<const float4*>(hidden + (size_t)b * S_ * H_);
  for (int i = 0; i < n; ++i) {
    const int s = list[i];
    float4 v = hb[(size_t)s * (H_ / 4) + t];
    ax += v.x; ay += v.y; az += v.z; aw += v.w;
  }
  ushort4 hi, lo;
  hi.x = f2bf(ax); lo.x = f2bf(ax - bf2f(hi.x));
  hi.y = f2bf(ay); lo.y = f2bf(ay - bf2f(hi.y));
  hi.z = f2bf(az); lo.z = f2bf(az - bf2f(hi.z));
  hi.w = f2bf(aw); lo.w = f2bf(aw - bf2f(hi.w));
  *reinterpret_cast<ushort4*>(chi + (size_t)bm * H_ + t * 4) = hi;
  *reinterpret_cast<ushort4*>(clo + (size_t)bm * H_ + t * 4) = lo;
}

// ------- Kernel 3: cell2 = gelu(cell @ W^T + b), split-bf16 MFMA (3 products)
// A = cell [R_][H_] (K contiguous), B = W [out][K] (K contiguous) -> NT GEMM.
// Wave tile 32x64 (2x4 frags of 16x16), 4 waves 2x2 -> block 64x128; grid 32x8.
__global__ __launch_bounds__(256) void gemm_gelu(const unsigned short* __restrict__ Ahi,
                                                 const unsigned short* __restrict__ Alo,
                                                 const unsigned short* __restrict__ Bhi,
                                                 const unsigned short* __restrict__ Blo,
                                                 const float* __restrict__ bias,
                                                 float* __restrict__ C) {
  const int lane = threadIdx.x & 63;
  const int wid  = threadIdx.x >> 6;
  const int wm = wid >> 1, wn = wid & 1;
  const int rowBase = blockIdx.x * 64 + wm * 32;
  const int colBase = blockIdx.y * 128 + wn * 64;
  const int lr = lane & 15;   // row (A) / col (B) within fragment
  const int kg = lane >> 4;   // k-group (8 bf16 each)

  f32x4 acc[2][4];
  #pragma unroll
  for (int mi = 0; mi < 2; ++mi)
    #pragma unroll
    for (int ni = 0; ni < 4; ++ni)
      acc[mi][ni] = (f32x4){0.f, 0.f, 0.f, 0.f};

  for (int k0 = 0; k0 < H_; k0 += 32) {
    short8 ah[2], al[2], bh[4], bl[4];
    #pragma unroll
    for (int mi = 0; mi < 2; ++mi) {
      const size_t off = (size_t)(rowBase + mi * 16 + lr) * H_ + k0 + kg * 8;
      ah[mi] = *reinterpret_cast<const short8*>(Ahi + off);
      al[mi] = *reinterpret_cast<const short8*>(Alo + off);
    }
    #pragma unroll
    for (int ni = 0; ni < 4; ++ni) {
      const size_t off = (size_t)(colBase + ni * 16 + lr) * H_ + k0 + kg * 8;
      bh[ni] = *reinterpret_cast<const short8*>(Bhi + off);
      bl[ni] = *reinterpret_cast<const short8*>(Blo + off);
    }
    #pragma unroll
    for (int mi = 0; mi < 2; ++mi)
      #pragma unroll
      for (int ni = 0; ni < 4; ++ni) {
        acc[mi][ni] = __builtin_amdgcn_mfma_f32_16x16x32_bf16(ah[mi], bh[ni], acc[mi][ni], 0, 0, 0);
        acc[mi][ni] = __builtin_amdgcn_mfma_f32_16x16x32_bf16(ah[mi], bl[ni], acc[mi][ni], 0, 0, 0);
        acc[mi][ni] = __builtin_amdgcn_mfma_f32_16x16x32_bf16(al[mi], bh[ni], acc[mi][ni], 0, 0, 0);
      }
  }

  const float cg = 0.7978845608028654f;  // sqrt(2/pi)
  #pragma unroll
  for (int mi = 0; mi < 2; ++mi) {
    #pragma unroll
    for (int ni = 0; ni < 4; ++ni) {
      const int col = colBase + ni * 16 + lr;
      const float bv = bias[col];
      #pragma unroll
      for (int j = 0; j < 4; ++j) {
        const int row = rowBase + mi * 16 + kg * 4 + j;   // C/D: col=lane&15, row=(lane>>4)*4+j
        float x = acc[mi][ni][j] + bv;
        float g = 0.5f * x * (1.0f + tanhf(cg * (x + 0.044715f * x * x * x)));
        C[(size_t)row * H_ + col] = g;
      }
    }
  }
}

// ---------------- Kernel 4: gather rows back to sequence (8 rows/block) ------
__global__ __launch_bounds__(256) void gather_rows(const float* __restrict__ cell2,
                                                   const void* __restrict__ tt,
                                                   const int* __restrict__ flag,
                                                   float* __restrict__ out) {
  __shared__ int ids[8];
  const int r0 = blockIdx.x * 8;       // first of 8 rows (b*S+s)
  const int t  = threadIdx.x;
  if (t < 8) ids[t] = get_id(tt, *flag, r0 + t);
  __syncthreads();
  const int b = r0 >> 12;              // 8 rows never straddle a batch (4096|8)
  #pragma unroll
  for (int j = 0; j < 8; ++j) {
    const float4* src = reinterpret_cast<const float4*>(cell2 + (size_t)(b * M_ + ids[j]) * H_);
    float4* dst = reinterpret_cast<float4*>(out + (size_t)(r0 + j) * H_);
    dst[t] = src[t];
  }
}

extern "C" void kernel_launch(void* const* d_in, const int* in_sizes, int n_in,
                              void* d_out, int out_size, void* d_ws, size_t ws_size,
                              hipStream_t stream) {
  const float* hidden = (const float*)d_in[0];
  const void*  tt     = d_in[1];
  const float* W      = (const float*)d_in[2];
  const float* bias   = (const float*)d_in[3];
  float* out = (float*)d_out;

  char* ws = (char*)d_ws;
  int* flag = (int*)ws;
  unsigned short* chi = (unsigned short*)(ws + 256);
  unsigned short* clo = chi + (size_t)R_ * H_;
  unsigned short* whi = clo + (size_t)R_ * H_;
  unsigned short* wlo = whi + (size_t)H_ * H_;
  float*          cell2 = (float*)(wlo + (size_t)H_ * H_);

  wconv_detect<<<dim3(H_ * H_ / 1024), dim3(256), 0, stream>>>(W, (const unsigned int*)tt, whi, wlo, flag);
  seg_sum<<<dim3(R_), dim3(256), 0, stream>>>(hidden, tt, flag, chi, clo);
  gemm_gelu<<<dim3(R_ / 64, H_ / 128), dim3(256), 0, stream>>>(chi, clo, whi, wlo, bias, cell2);
  gather_rows<<<dim3(B_ * S_ / 8), dim3(256), 0, stream>>>(cell2, tt, flag, out);
}